// Round 1
// baseline (1184.560 us; speedup 1.0000x reference)
//
#include <hip/hip_runtime.h>
#include <math.h>

#define HW 6400
#define NC 512
#define NH 80
#define NW 80
#define NCHUNK 10   // j-splits of the 6400 columns
#define JCH 640     // columns per chunk
#define TI 128      // row tile
#define TJ 128      // col tile
#define KB 16       // K tile
#define LSTR 132    // LDS row stride (float4-aligned)

// workspace layout (float offsets)
#define MU_OFF      0
#define SXI_OFF     (NC)
#define SYI_OFF     (NC + HW)
#define GMAXP_OFF   (NC + 2*HW)                 // HW*NCHUNK
#define INVD_OFF    (GMAXP_OFF + HW*NCHUNK)
#define ZP_OFF      (INVD_OFF + HW)             // HW*NCHUNK
#define WMAXP_OFF   (ZP_OFF + HW*NCHUNK)        // HW*NCHUNK
#define WDIAGP_OFF  (WMAXP_OFF + HW*NCHUNK)     // HW*NCHUNK
#define ACC_OFF     (WDIAGP_OFF + HW*NCHUNK)

__global__ void k_mu(const float* __restrict__ y, float* __restrict__ mu) {
    int c = blockIdx.x;
    const float* yc = y + (size_t)c * HW;
    float s = 0.f;
    for (int i = threadIdx.x; i < HW; i += 256) s += yc[i];
    __shared__ float red[256];
    red[threadIdx.x] = s;
    __syncthreads();
    for (int off = 128; off > 0; off >>= 1) {
        if (threadIdx.x < off) red[threadIdx.x] += red[threadIdx.x + off];
        __syncthreads();
    }
    if (threadIdx.x == 0) mu[c] = red[0] * (1.0f / HW);
}

__global__ void k_norms(const float* __restrict__ x, const float* __restrict__ y,
                        const float* __restrict__ mu,
                        float* __restrict__ sxi, float* __restrict__ syi) {
    __shared__ float smu[NC];
    for (int c = threadIdx.x; c < NC; c += 256) smu[c] = mu[c];
    __syncthreads();
    int i = blockIdx.x * 256 + threadIdx.x;
    float sx = 0.f, sy = 0.f;
    for (int c = 0; c < NC; ++c) {
        float m = smu[c];
        float dx = x[(size_t)c * HW + i] - m;
        float dy = y[(size_t)c * HW + i] - m;
        sx = fmaf(dx, dx, sx);
        sy = fmaf(dy, dy, sy);
    }
    sxi[i] = 1.0f / fmaxf(sqrtf(sx), 1e-12f);
    syi[i] = 1.0f / fmaxf(sqrtf(sy), 1e-12f);
}

// Shared GEMM-tile driver: computes 128x128 blocks of G = Xn^T * Yn for this
// block's row tile (blockIdx.x) over its column chunk (blockIdx.y), calling
// consume(acc, jt) after each 128x128 tile. Normalization fused into staging.
template <typename F>
__device__ __forceinline__ void gemm_rows(const float* __restrict__ x,
                                          const float* __restrict__ y,
                                          const float* __restrict__ mu,
                                          const float* __restrict__ sxi,
                                          const float* __restrict__ syi,
                                          F&& consume) {
    __shared__ float Xs[KB][LSTR];
    __shared__ float Ys[KB][LSTR];
    __shared__ float smu[NC];
    __shared__ float ssx[TI];
    __shared__ float ssy[JCH];

    const int t = threadIdx.x;
    const int i0 = blockIdx.x * TI;
    const int jbase = blockIdx.y * JCH;

    for (int c = t; c < NC; c += 256) smu[c] = mu[c];
    for (int v = t; v < TI; v += 256) ssx[v] = sxi[i0 + v];
    for (int v = t; v < JCH; v += 256) ssy[v] = syi[jbase + v];

    const int tx = t & 15, ty = t >> 4;

    for (int jt = 0; jt < JCH; jt += TJ) {
        float acc[8][8];
        #pragma unroll
        for (int a = 0; a < 8; ++a)
            #pragma unroll
            for (int b = 0; b < 8; ++b) acc[a][b] = 0.f;

        for (int kt = 0; kt < NC; kt += KB) {
            __syncthreads();   // also covers the preload on first iteration
            #pragma unroll
            for (int l = 0; l < 2; ++l) {
                int idx = t + l * 256;
                int row = idx >> 5;
                int col = (idx & 31) * 4;
                float m = smu[kt + row];
                float4 xv = *(const float4*)(x + (size_t)(kt + row) * HW + i0 + col);
                float4 yv = *(const float4*)(y + (size_t)(kt + row) * HW + jbase + jt + col);
                float4 xr, yr;
                xr.x = (xv.x - m) * ssx[col + 0];
                xr.y = (xv.y - m) * ssx[col + 1];
                xr.z = (xv.z - m) * ssx[col + 2];
                xr.w = (xv.w - m) * ssx[col + 3];
                yr.x = (yv.x - m) * ssy[jt + col + 0];
                yr.y = (yv.y - m) * ssy[jt + col + 1];
                yr.z = (yv.z - m) * ssy[jt + col + 2];
                yr.w = (yv.w - m) * ssy[jt + col + 3];
                *(float4*)&Xs[row][col] = xr;
                *(float4*)&Ys[row][col] = yr;
            }
            __syncthreads();
            #pragma unroll
            for (int kb = 0; kb < KB; ++kb) {
                float4 a0 = *(const float4*)&Xs[kb][ty * 4];
                float4 a1 = *(const float4*)&Xs[kb][ty * 4 + 64];
                float4 b0 = *(const float4*)&Ys[kb][tx * 4];
                float4 b1 = *(const float4*)&Ys[kb][tx * 4 + 64];
                float av[8] = {a0.x, a0.y, a0.z, a0.w, a1.x, a1.y, a1.z, a1.w};
                float bv[8] = {b0.x, b0.y, b0.z, b0.w, b1.x, b1.y, b1.z, b1.w};
                #pragma unroll
                for (int a = 0; a < 8; ++a)
                    #pragma unroll
                    for (int b = 0; b < 8; ++b)
                        acc[a][b] = fmaf(av[a], bv[b], acc[a][b]);
            }
        }
        consume(acc, jt);
    }
}

__global__ __launch_bounds__(256, 2) void k_pass1(const float* __restrict__ x,
                                                  const float* __restrict__ y,
                                                  const float* __restrict__ mu,
                                                  const float* __restrict__ sxi,
                                                  const float* __restrict__ syi,
                                                  float* __restrict__ gmaxp) {
    const int t = threadIdx.x;
    const int tx = t & 15, ty = t >> 4;
    const int i0 = blockIdx.x * TI;
    float gmax[8];
    #pragma unroll
    for (int u = 0; u < 8; ++u) gmax[u] = -3.0e38f;

    gemm_rows(x, y, mu, sxi, syi, [&](float (&acc)[8][8], int jt) {
        (void)jt;
        #pragma unroll
        for (int a = 0; a < 8; ++a)
            #pragma unroll
            for (int b = 0; b < 8; ++b) gmax[a] = fmaxf(gmax[a], acc[a][b]);
    });

    #pragma unroll
    for (int u = 0; u < 8; ++u) {
        float v = gmax[u];
        v = fmaxf(v, __shfl_xor(v, 1));
        v = fmaxf(v, __shfl_xor(v, 2));
        v = fmaxf(v, __shfl_xor(v, 4));
        v = fmaxf(v, __shfl_xor(v, 8));
        if (tx == 0) {
            int il = (u < 4) ? (ty * 4 + u) : (64 + ty * 4 + (u - 4));
            gmaxp[(size_t)(i0 + il) * NCHUNK + blockIdx.y] = v;
        }
    }
}

__global__ void k_invd(const float* __restrict__ gmaxp, float* __restrict__ invd) {
    int i = blockIdx.x * 256 + threadIdx.x;
    float m = -3.0e38f;
    #pragma unroll
    for (int s = 0; s < NCHUNK; ++s) m = fmaxf(m, gmaxp[(size_t)i * NCHUNK + s]);
    invd[i] = 1.0f / ((1.0f - m) + 1e-5f);   // dmin = 1 - max_j cos
}

__global__ __launch_bounds__(256, 2) void k_pass2(const float* __restrict__ x,
                                                  const float* __restrict__ y,
                                                  const float* __restrict__ mu,
                                                  const float* __restrict__ sxi,
                                                  const float* __restrict__ syi,
                                                  const float* __restrict__ invd,
                                                  float* __restrict__ zp,
                                                  float* __restrict__ wmp,
                                                  float* __restrict__ wdp) {
    const int t = threadIdx.x;
    const int tx = t & 15, ty = t >> 4;
    const int i0 = blockIdx.x * TI;
    const int jbase = blockIdx.y * JCH;

    float invr[8], zsum[8], wmax[8], wdiag[8];
    #pragma unroll
    for (int u = 0; u < 8; ++u) {
        int il = (u < 4) ? (ty * 4 + u) : (64 + ty * 4 + (u - 4));
        invr[u] = invd[i0 + il];
        zsum[u] = 0.f; wmax[u] = 0.f; wdiag[u] = 0.f;
    }

    gemm_rows(x, y, mu, sxi, syi, [&](float (&acc)[8][8], int jt) {
        #pragma unroll
        for (int a = 0; a < 8; ++a) {
            int il = (a < 4) ? (ty * 4 + a) : (64 + ty * 4 + (a - 4));
            int ig = i0 + il;
            float inv = invr[a];
            #pragma unroll
            for (int b = 0; b < 8; ++b) {
                int jl = (b < 4) ? (tx * 4 + b) : (64 + tx * 4 + (b - 4));
                int jg = jbase + jt + jl;
                float d = 1.0f - acc[a][b];
                float w = __expf(2.0f - 2.0f * d * inv);
                zsum[a] += w;
                wmax[a] = fmaxf(wmax[a], w);
                if (jg == ig) wdiag[a] = w;
            }
        }
    });

    #pragma unroll
    for (int u = 0; u < 8; ++u) {
        float z = zsum[u], wm = wmax[u], wd = wdiag[u];
        z += __shfl_xor(z, 1);  wm = fmaxf(wm, __shfl_xor(wm, 1));  wd += __shfl_xor(wd, 1);
        z += __shfl_xor(z, 2);  wm = fmaxf(wm, __shfl_xor(wm, 2));  wd += __shfl_xor(wd, 2);
        z += __shfl_xor(z, 4);  wm = fmaxf(wm, __shfl_xor(wm, 4));  wd += __shfl_xor(wd, 4);
        z += __shfl_xor(z, 8);  wm = fmaxf(wm, __shfl_xor(wm, 8));  wd += __shfl_xor(wd, 8);
        if (tx == 0) {
            int il = (u < 4) ? (ty * 4 + u) : (64 + ty * 4 + (u - 4));
            size_t row = (size_t)(i0 + il) * NCHUNK + blockIdx.y;
            zp[row] = z; wmp[row] = wm; wdp[row] = wd;
        }
    }
}

__global__ void k_kmax(const float* __restrict__ zp, const float* __restrict__ wmp,
                       const float* __restrict__ wdp, float* __restrict__ accum) {
    int i = blockIdx.x * 256 + threadIdx.x;
    float Z = 0.f, wm = 0.f, wd = 0.f;
    #pragma unroll
    for (int s = 0; s < NCHUNK; ++s) {
        Z += zp[(size_t)i * NCHUNK + s];
        wm = fmaxf(wm, wmp[(size_t)i * NCHUNK + s]);
        wd += wdp[(size_t)i * NCHUNK + s];
    }
    // exact spatial diagonal weight: cx_sp[i,i] = 1/(SR(r)*SC(c))
    int r = i / NW, c = i % NW;
    double aa = 200000.0 / 6561.0;  // 2/bw * 1e5 * (1/81)^2 with bw=0.5
    double SR = 0.0, SC = 0.0;
    for (int k = 0; k < NH; ++k) {
        double dr = (double)(r - k);
        double dc = (double)(c - k);
        SR += exp(-aa * dr * dr);
        SC += exp(-aa * dc * dc);
    }
    float sp = (float)(1.0 / (SR * SC));
    float invZ = 1.0f / Z;
    float kmax = fmaxf(0.9f * wm * invZ, 0.9f * wd * invZ + 0.1f * sp);

    __shared__ float red[256];
    red[threadIdx.x] = kmax;
    __syncthreads();
    for (int off = 128; off > 0; off >>= 1) {
        if (threadIdx.x < off) red[threadIdx.x] += red[threadIdx.x + off];
        __syncthreads();
    }
    if (threadIdx.x == 0) atomicAdd(accum, red[0]);
}

__global__ void k_final(const float* __restrict__ accum, float* __restrict__ out) {
    out[0] = -logf(accum[0] * (1.0f / HW) + 1e-5f);
}

extern "C" void kernel_launch(void* const* d_in, const int* in_sizes, int n_in,
                              void* d_out, int out_size, void* d_ws, size_t ws_size,
                              hipStream_t stream) {
    const float* x = (const float*)d_in[0];
    const float* y = (const float*)d_in[1];
    float* out = (float*)d_out;
    float* ws = (float*)d_ws;

    float* mu    = ws + MU_OFF;
    float* sxi   = ws + SXI_OFF;
    float* syi   = ws + SYI_OFF;
    float* gmaxp = ws + GMAXP_OFF;
    float* invd  = ws + INVD_OFF;
    float* zp    = ws + ZP_OFF;
    float* wmp   = ws + WMAXP_OFF;
    float* wdp   = ws + WDIAGP_OFF;
    float* accum = ws + ACC_OFF;

    hipMemsetAsync(accum, 0, sizeof(float), stream);

    hipLaunchKernelGGL(k_mu, dim3(NC), dim3(256), 0, stream, y, mu);
    hipLaunchKernelGGL(k_norms, dim3(HW / 256), dim3(256), 0, stream, x, y, mu, sxi, syi);

    dim3 grid(HW / TI, NCHUNK);
    hipLaunchKernelGGL(k_pass1, grid, dim3(256), 0, stream, x, y, mu, sxi, syi, gmaxp);
    hipLaunchKernelGGL(k_invd, dim3(HW / 256), dim3(256), 0, stream, gmaxp, invd);
    hipLaunchKernelGGL(k_pass2, grid, dim3(256), 0, stream, x, y, mu, sxi, syi, invd, zp, wmp, wdp);
    hipLaunchKernelGGL(k_kmax, dim3(HW / 256), dim3(256), 0, stream, zp, wmp, wdp, accum);
    hipLaunchKernelGGL(k_final, dim3(1), dim3(1), 0, stream, accum, out);
}

// Round 2
// 232.912 us; speedup vs baseline: 5.0859x; 5.0859x over previous
//
#include <hip/hip_runtime.h>
#include <hip/hip_bf16.h>
#include <math.h>

#define HW 6400
#define NC 512
#define NH 80
#define NW 80
#define NCHUNK 10
#define JCH 640
#define TI 128
#define BK 64

typedef __attribute__((ext_vector_type(8))) short short8;
typedef __attribute__((ext_vector_type(4))) float v4f;

// ---- workspace layout (float offsets for fp32 region) ----
#define MU_OFF    0
#define SXI_OFF   (NC)
#define SYI_OFF   (NC + HW)
#define GMAXP_OFF (NC + 2*HW)
#define INVD_OFF  (GMAXP_OFF + HW*NCHUNK)
#define ZP_OFF    (INVD_OFF + HW)
#define WMP_OFF   (ZP_OFF + HW*NCHUNK)
#define WDP_OFF   (WMP_OFF + HW*NCHUNK)
#define ACC_OFF   (WDP_OFF + HW*NCHUNK)
#define F32_FLOATS (ACC_OFF + 64)
// bf16 region (byte offsets from ws base)
#define XB_BYTE   ((size_t)(((F32_FLOATS*4) + 255) & ~255))
#define YB_BYTE   (XB_BYTE + (size_t)HW*NC*2)

__global__ void k_mu(const float* __restrict__ y, float* __restrict__ mu) {
    int c = blockIdx.x;
    const float* yc = y + (size_t)c * HW;
    float s = 0.f;
    for (int i = threadIdx.x; i < HW; i += 256) s += yc[i];
    __shared__ float red[256];
    red[threadIdx.x] = s;
    __syncthreads();
    for (int off = 128; off > 0; off >>= 1) {
        if (threadIdx.x < off) red[threadIdx.x] += red[threadIdx.x + off];
        __syncthreads();
    }
    if (threadIdx.x == 0) mu[c] = red[0] * (1.0f / HW);
}

__global__ void k_norms(const float* __restrict__ x, const float* __restrict__ y,
                        const float* __restrict__ mu,
                        float* __restrict__ sxi, float* __restrict__ syi) {
    __shared__ float smu[NC];
    for (int c = threadIdx.x; c < NC; c += 256) smu[c] = mu[c];
    __syncthreads();
    int i = blockIdx.x * 256 + threadIdx.x;
    float sx = 0.f, sy = 0.f;
    for (int c = 0; c < NC; ++c) {
        float m = smu[c];
        float dx = x[(size_t)c * HW + i] - m;
        float dy = y[(size_t)c * HW + i] - m;
        sx = fmaf(dx, dx, sx);
        sy = fmaf(dy, dy, sy);
    }
    sxi[i] = 1.0f / fmaxf(sqrtf(sx), 1e-12f);
    syi[i] = 1.0f / fmaxf(sqrtf(sy), 1e-12f);
}

// normalized bf16 transpose: src [c][i] fp32 -> dst [i][c] bf16 ((v-mu)*sinv)
__global__ void k_transpose(const float* __restrict__ src, const float* __restrict__ mu,
                            const float* __restrict__ sinv, unsigned short* __restrict__ dst) {
    __shared__ float tile[64 * 68];
    const int t = threadIdx.x;
    const int i0 = blockIdx.x * 64;
    const int c0 = blockIdx.y * 64;
    #pragma unroll 4
    for (int it = 0; it < 16; ++it) {
        int cl = it * 4 + (t >> 6);
        int il = t & 63;
        float v = (src[(size_t)(c0 + cl) * HW + i0 + il] - mu[c0 + cl]) * sinv[i0 + il];
        tile[il * 68 + cl] = v;
    }
    __syncthreads();
    #pragma unroll
    for (int it = 0; it < 2; ++it) {
        int il = t >> 2;
        int seg = (t & 3) + it * 4;
        unsigned int pk[4];
        #pragma unroll
        for (int p = 0; p < 4; ++p) {
            float v0 = tile[il * 68 + seg * 8 + p * 2];
            float v1 = tile[il * 68 + seg * 8 + p * 2 + 1];
            __hip_bfloat16 h0 = __float2bfloat16(v0);
            __hip_bfloat16 h1 = __float2bfloat16(v1);
            unsigned short u0 = *reinterpret_cast<unsigned short*>(&h0);
            unsigned short u1 = *reinterpret_cast<unsigned short*>(&h1);
            pk[p] = (unsigned int)u0 | ((unsigned int)u1 << 16);
        }
        uint4 val = make_uint4(pk[0], pk[1], pk[2], pk[3]);
        *(uint4*)&dst[(size_t)(i0 + il) * NC + c0 + seg * 8] = val;
    }
}

// MFMA GEMM driver: block computes rows [i0,i0+128) x cols [jbase, jbase+640)
// in 128x128 tiles; calls consume(acc, jt) per tile. Wave w owns rows w*32..+31.
template <typename F>
__device__ __forceinline__ void gemm_driver(const unsigned short* __restrict__ Xb,
                                            const unsigned short* __restrict__ Yb,
                                            F&& consume) {
    __shared__ char sA[TI * BK * 2];   // [row][k] bf16, 128B/row, seg^=(row&7) swizzle
    __shared__ char sB[TI * BK * 2];
    const int t = threadIdx.x;
    const int w = t >> 6, l = t & 63;
    const int lr = l & 15, lg = l >> 4;
    const int i0 = blockIdx.x * TI;
    const int jbase = blockIdx.y * JCH;

    // precomputed swizzled LDS read offsets (kt-invariant)
    int aoff[2][2], boff[8][2];
    #pragma unroll
    for (int mt = 0; mt < 2; ++mt) {
        int row = w * 32 + mt * 16 + lr;
        #pragma unroll
        for (int ks = 0; ks < 2; ++ks) {
            int seg = ks * 4 + lg;
            aoff[mt][ks] = row * 128 + ((seg ^ (row & 7)) * 16);
        }
    }
    #pragma unroll
    for (int nt = 0; nt < 8; ++nt) {
        int row = nt * 16 + lr;
        #pragma unroll
        for (int ks = 0; ks < 2; ++ks) {
            int seg = ks * 4 + lg;
            boff[nt][ks] = row * 128 + ((seg ^ (row & 7)) * 16);
        }
    }
    // staging: thread t handles chunks t, t+256, t+512, t+768 (chunk = row*8+seg)
    int srow[4], swoff[4];
    #pragma unroll
    for (int it = 0; it < 4; ++it) {
        int c = t + it * 256;
        srow[it] = c >> 3;
        swoff[it] = srow[it] * 128 + (((c & 7) ^ (srow[it] & 7)) * 16);
    }
    const int sseg8 = (t & 7) * 8;   // k-element offset of this thread's chunk

    #pragma unroll 1
    for (int jt = 0; jt < JCH; jt += TI) {
        v4f acc[2][8];
        #pragma unroll
        for (int mt = 0; mt < 2; ++mt)
            #pragma unroll
            for (int nt = 0; nt < 8; ++nt)
                acc[mt][nt] = (v4f){0.f, 0.f, 0.f, 0.f};

        #pragma unroll 1
        for (int kt = 0; kt < NC; kt += BK) {
            __syncthreads();
            uint4 av[4], bv[4];
            #pragma unroll
            for (int it = 0; it < 4; ++it) {
                av[it] = *(const uint4*)(Xb + (size_t)(i0 + srow[it]) * NC + kt + sseg8);
                bv[it] = *(const uint4*)(Yb + (size_t)(jbase + jt + srow[it]) * NC + kt + sseg8);
            }
            #pragma unroll
            for (int it = 0; it < 4; ++it) {
                *(uint4*)&sA[swoff[it]] = av[it];
                *(uint4*)&sB[swoff[it]] = bv[it];
            }
            __syncthreads();
            #pragma unroll
            for (int ks = 0; ks < 2; ++ks) {
                short8 af[2], bf[8];
                af[0] = *(const short8*)&sA[aoff[0][ks]];
                af[1] = *(const short8*)&sA[aoff[1][ks]];
                #pragma unroll
                for (int nt = 0; nt < 8; ++nt) bf[nt] = *(const short8*)&sB[boff[nt][ks]];
                #pragma unroll
                for (int mt = 0; mt < 2; ++mt)
                    #pragma unroll
                    for (int nt = 0; nt < 8; ++nt)
                        acc[mt][nt] = __builtin_amdgcn_mfma_f32_16x16x32_bf16(
                            af[mt], bf[nt], acc[mt][nt], 0, 0, 0);
            }
        }
        consume(acc, jt);
    }
}

__global__ __launch_bounds__(256, 2) void k_pass1(const unsigned short* __restrict__ Xb,
                                                  const unsigned short* __restrict__ Yb,
                                                  float* __restrict__ gmaxp) {
    const int t = threadIdx.x;
    const int w = t >> 6, l = t & 63, lr = l & 15, lg = l >> 4;
    const int i0 = blockIdx.x * TI;
    float rmax[8];
    #pragma unroll
    for (int u = 0; u < 8; ++u) rmax[u] = -3.0e38f;

    gemm_driver(Xb, Yb, [&](v4f (&acc)[2][8], int jt) {
        (void)jt;
        #pragma unroll
        for (int mt = 0; mt < 2; ++mt)
            #pragma unroll
            for (int r = 0; r < 4; ++r) {
                float m = acc[mt][0][r];
                #pragma unroll
                for (int nt = 1; nt < 8; ++nt) m = fmaxf(m, acc[mt][nt][r]);
                rmax[mt * 4 + r] = fmaxf(rmax[mt * 4 + r], m);
            }
    });

    #pragma unroll
    for (int u = 0; u < 8; ++u) {
        float v = rmax[u];
        v = fmaxf(v, __shfl_xor(v, 1));
        v = fmaxf(v, __shfl_xor(v, 2));
        v = fmaxf(v, __shfl_xor(v, 4));
        v = fmaxf(v, __shfl_xor(v, 8));
        if (lr == 0) {
            int row = i0 + w * 32 + (u >> 2) * 16 + lg * 4 + (u & 3);
            gmaxp[(size_t)row * NCHUNK + blockIdx.y] = v;
        }
    }
}

__global__ void k_invd(const float* __restrict__ gmaxp, float* __restrict__ invd) {
    int i = blockIdx.x * 256 + threadIdx.x;
    float m = -3.0e38f;
    #pragma unroll
    for (int s = 0; s < NCHUNK; ++s) m = fmaxf(m, gmaxp[(size_t)i * NCHUNK + s]);
    invd[i] = 1.0f / ((1.0f - m) + 1e-5f);
}

__global__ __launch_bounds__(256, 2) void k_pass2(const unsigned short* __restrict__ Xb,
                                                  const unsigned short* __restrict__ Yb,
                                                  const float* __restrict__ invd,
                                                  float* __restrict__ zp,
                                                  float* __restrict__ wmp,
                                                  float* __restrict__ wdp) {
    const int t = threadIdx.x;
    const int w = t >> 6, l = t & 63, lr = l & 15, lg = l >> 4;
    const int i0 = blockIdx.x * TI;
    const int jbase = blockIdx.y * JCH;

    float zs[8], wm[8], wd[8], invr[8];
    #pragma unroll
    for (int u = 0; u < 8; ++u) {
        int row = i0 + w * 32 + (u >> 2) * 16 + lg * 4 + (u & 3);
        invr[u] = invd[row];
        zs[u] = 0.f; wm[u] = 0.f; wd[u] = 0.f;
    }

    gemm_driver(Xb, Yb, [&](v4f (&acc)[2][8], int jt) {
        #pragma unroll
        for (int mt = 0; mt < 2; ++mt)
            #pragma unroll
            for (int r = 0; r < 4; ++r) {
                int u = mt * 4 + r;
                int ig = i0 + w * 32 + mt * 16 + lg * 4 + r;
                float inv = invr[u];
                #pragma unroll
                for (int nt = 0; nt < 8; ++nt) {
                    int jg = jbase + jt + nt * 16 + lr;
                    float g = acc[mt][nt][r];
                    float wv = __expf(2.0f - 2.0f * (1.0f - g) * inv);
                    zs[u] += wv;
                    wm[u] = fmaxf(wm[u], wv);
                    if (jg == ig) wd[u] = wv;
                }
            }
    });

    #pragma unroll
    for (int u = 0; u < 8; ++u) {
        float z = zs[u], m = wm[u], d = wd[u];
        z += __shfl_xor(z, 1);  m = fmaxf(m, __shfl_xor(m, 1));  d += __shfl_xor(d, 1);
        z += __shfl_xor(z, 2);  m = fmaxf(m, __shfl_xor(m, 2));  d += __shfl_xor(d, 2);
        z += __shfl_xor(z, 4);  m = fmaxf(m, __shfl_xor(m, 4));  d += __shfl_xor(d, 4);
        z += __shfl_xor(z, 8);  m = fmaxf(m, __shfl_xor(m, 8));  d += __shfl_xor(d, 8);
        if (lr == 0) {
            int row = i0 + w * 32 + (u >> 2) * 16 + lg * 4 + (u & 3);
            size_t o = (size_t)row * NCHUNK + blockIdx.y;
            zp[o] = z; wmp[o] = m; wdp[o] = d;
        }
    }
}

__global__ void k_kmax(const float* __restrict__ zp, const float* __restrict__ wmp,
                       const float* __restrict__ wdp, float* __restrict__ accum) {
    int i = blockIdx.x * 256 + threadIdx.x;
    float Z = 0.f, wmx = 0.f, wdg = 0.f;
    #pragma unroll
    for (int s = 0; s < NCHUNK; ++s) {
        Z += zp[(size_t)i * NCHUNK + s];
        wmx = fmaxf(wmx, wmp[(size_t)i * NCHUNK + s]);
        wdg += wdp[(size_t)i * NCHUNK + s];
    }
    int r = i / NW, c = i % NW;
    double aa = 200000.0 / 6561.0;
    double SR = 0.0, SC = 0.0;
    for (int k = 0; k < NH; ++k) {
        double dr = (double)(r - k);
        double dc = (double)(c - k);
        SR += exp(-aa * dr * dr);
        SC += exp(-aa * dc * dc);
    }
    float sp = (float)(1.0 / (SR * SC));
    float invZ = 1.0f / Z;
    float kmax = fmaxf(0.9f * wmx * invZ, 0.9f * wdg * invZ + 0.1f * sp);

    __shared__ float red[256];
    red[threadIdx.x] = kmax;
    __syncthreads();
    for (int off = 128; off > 0; off >>= 1) {
        if (threadIdx.x < off) red[threadIdx.x] += red[threadIdx.x + off];
        __syncthreads();
    }
    if (threadIdx.x == 0) atomicAdd(accum, red[0]);
}

__global__ void k_final(const float* __restrict__ accum, float* __restrict__ out) {
    out[0] = -logf(accum[0] * (1.0f / HW) + 1e-5f);
}

extern "C" void kernel_launch(void* const* d_in, const int* in_sizes, int n_in,
                              void* d_out, int out_size, void* d_ws, size_t ws_size,
                              hipStream_t stream) {
    const float* x = (const float*)d_in[0];
    const float* y = (const float*)d_in[1];
    float* out = (float*)d_out;
    float* ws = (float*)d_ws;

    float* mu    = ws + MU_OFF;
    float* sxi   = ws + SXI_OFF;
    float* syi   = ws + SYI_OFF;
    float* gmaxp = ws + GMAXP_OFF;
    float* invd  = ws + INVD_OFF;
    float* zp    = ws + ZP_OFF;
    float* wmp   = ws + WMP_OFF;
    float* wdp   = ws + WDP_OFF;
    float* accum = ws + ACC_OFF;
    unsigned short* Xb = (unsigned short*)((char*)d_ws + XB_BYTE);
    unsigned short* Yb = (unsigned short*)((char*)d_ws + YB_BYTE);

    hipMemsetAsync(accum, 0, sizeof(float), stream);

    hipLaunchKernelGGL(k_mu, dim3(NC), dim3(256), 0, stream, y, mu);
    hipLaunchKernelGGL(k_norms, dim3(HW / 256), dim3(256), 0, stream, x, y, mu, sxi, syi);
    hipLaunchKernelGGL(k_transpose, dim3(HW / 64, NC / 64), dim3(256), 0, stream, x, mu, sxi, Xb);
    hipLaunchKernelGGL(k_transpose, dim3(HW / 64, NC / 64), dim3(256), 0, stream, y, mu, syi, Yb);

    dim3 grid(HW / TI, NCHUNK);
    hipLaunchKernelGGL(k_pass1, grid, dim3(256), 0, stream, Xb, Yb, gmaxp);
    hipLaunchKernelGGL(k_invd, dim3(HW / 256), dim3(256), 0, stream, gmaxp, invd);
    hipLaunchKernelGGL(k_pass2, grid, dim3(256), 0, stream, Xb, Yb, invd, zp, wmp, wdp);
    hipLaunchKernelGGL(k_kmax, dim3(HW / 256), dim3(256), 0, stream, zp, wmp, wdp, accum);
    hipLaunchKernelGGL(k_final, dim3(1), dim3(1), 0, stream, accum, out);
}